// Round 1
// baseline (932.836 us; speedup 1.0000x reference)
//
#include <hip/hip_runtime.h>

#define HID 128

// ---------------------------------------------------------------- degrees
__global__ void degrees_kernel(const int* __restrict__ s0, const int* __restrict__ d0,
                               const int* __restrict__ s1, const int* __restrict__ d1,
                               int* __restrict__ dout0, int* __restrict__ din0,
                               int* __restrict__ dout1, int* __restrict__ din1, int E) {
    int i = blockIdx.x * blockDim.x + threadIdx.x;
    if (i >= E) return;
    atomicAdd(&dout0[s0[i]], 1);
    atomicAdd(&din0[d0[i]], 1);
    atomicAdd(&dout1[s1[i]], 1);
    atomicAdd(&din1[d1[i]], 1);
}

// ---------------------------------------------------------------- fused weights: M = We@W1, cv = be@W1
__global__ __launch_bounds__(256) void weight_fuse(
    const float* __restrict__ We,  // [256,128]
    const float* __restrict__ be,  // [128]
    const float* __restrict__ W1,  // [128,128]
    float* __restrict__ M,         // [256,128]
    float* __restrict__ cv)        // [128]
{
    __shared__ float w1[128][128];  // 64 KB
    int tid = threadIdx.x;
    #pragma unroll
    for (int it = 0; it < 16; ++it) {           // 4096 float4 slots / 256 thr
        int s = tid + it * 256;
        int r = s >> 5, c4 = (s & 31) << 2;
        *(float4*)&w1[r][c4] = *(const float4*)&W1[r * 128 + c4];
    }
    __syncthreads();
    int j = tid & 127;
    int half = tid >> 7;
    if (blockIdx.x == 128) {                    // bias row
        if (half) return;
        float sum = 0.f;
        for (int k = 0; k < 128; ++k) sum += be[k] * w1[k][j];
        cv[j] = sum;
        return;
    }
    int i = blockIdx.x * 2 + half;
    const float* arow = &We[i * 128];
    float sum = 0.f;
    for (int k = 0; k < 128; ++k) sum += arow[k] * w1[k][j];
    M[i * 128 + j] = sum;
}

// ---------------------------------------------------------------- scan (exclusive prefix sum of deg -> rowptr)
__global__ __launch_bounds__(256) void scan_a(const int* __restrict__ deg, int* __restrict__ loc,
                                              int* __restrict__ partials, int n) {
    __shared__ int sdata[256];
    int b = blockIdx.x;
    int base = b * 1024;
    int tid = threadIdx.x;
    int v[4]; int s = 0;
    #pragma unroll
    for (int i = 0; i < 4; ++i) { int idx = base + tid * 4 + i; v[i] = (idx < n) ? deg[idx] : 0; s += v[i]; }
    sdata[tid] = s; __syncthreads();
    for (int off = 1; off < 256; off <<= 1) {
        int t = (tid >= off) ? sdata[tid - off] : 0; __syncthreads();
        sdata[tid] += t; __syncthreads();
    }
    int excl = sdata[tid] - s;
    if (tid == 255) partials[b] = sdata[255];
    int run = excl;
    #pragma unroll
    for (int i = 0; i < 4; ++i) { int idx = base + tid * 4 + i; if (idx < n) loc[idx] = run; run += v[i]; }
}

__global__ __launch_bounds__(128) void scan_b(int* __restrict__ partials, int nb) {
    __shared__ int sdata[128];
    int tid = threadIdx.x;
    int v = (tid < nb) ? partials[tid] : 0;
    sdata[tid] = v; __syncthreads();
    for (int off = 1; off < 128; off <<= 1) {
        int t = (tid >= off) ? sdata[tid - off] : 0; __syncthreads();
        sdata[tid] += t; __syncthreads();
    }
    if (tid < nb) partials[tid] = sdata[tid] - v;
}

__global__ __launch_bounds__(256) void scan_c(int* __restrict__ rowptr, const int* __restrict__ partials,
                                              int* __restrict__ cursor, int n, int E) {
    int i = blockIdx.x * 256 + threadIdx.x;
    if (i < n) {
        int v = rowptr[i] + partials[i >> 10];
        rowptr[i] = v;
        cursor[i] = v;
    }
    if (i == n) rowptr[n] = E;
}

// ---------------------------------------------------------------- CSR fill (by dst, stores src node id)
__global__ void csr_fill(const int* __restrict__ src, const int* __restrict__ dst,
                         int* __restrict__ cursor, int* __restrict__ csr, int E) {
    int e = blockIdx.x * blockDim.x + threadIdx.x;
    if (e >= E) return;
    int d = dst[e];
    int pos = atomicAdd(&cursor[d], 1);
    csr[pos] = src[e];
}

// ---------------------------------------------------------------- GEMM: T = (X @ M + cv) * rsqrt(max(deg,1)) per row
// X:[n,K], M:[K,128]; block computes 64 rows x 128 cols; 256 thr = 16x16, each 4 rows x 8 cols
template <int K>
__global__ __launch_bounds__(256) void gemm_rowscale(
    const float* __restrict__ X, const float* __restrict__ M,
    const float* __restrict__ cvec, const int* __restrict__ degs,
    float* __restrict__ T, int n)
{
    __shared__ float xs[64][68];   // +4 pad keeps float4 alignment, kills 4-way conflicts
    __shared__ float ms[64][128];
    const int tid = threadIdx.x;
    const int c16 = tid & 15;
    const int r16 = tid >> 4;
    const int row0 = blockIdx.x * 64;

    float acc[4][8];
    #pragma unroll
    for (int i = 0; i < 4; ++i)
        #pragma unroll
        for (int j = 0; j < 8; ++j) acc[i][j] = 0.f;

    for (int kc = 0; kc < K; kc += 64) {
        __syncthreads();
        // stage X tile: 64 rows x 64 k
        #pragma unroll
        for (int it = 0; it < 4; ++it) {
            int s = tid + it * 256;            // 0..1023
            int r = s >> 4;
            int k4 = (s & 15) << 2;
            int grow = row0 + r;
            float4 v = make_float4(0.f, 0.f, 0.f, 0.f);
            if (grow < n) v = *(const float4*)&X[(size_t)grow * K + kc + k4];
            *(float4*)&xs[r][k4] = v;
        }
        // stage M tile: 64 k x 128 cols
        #pragma unroll
        for (int it = 0; it < 8; ++it) {
            int s = tid + it * 256;            // 0..2047
            int r = s >> 5;
            int c4 = (s & 31) << 2;
            *(float4*)&ms[r][c4] = *(const float4*)&M[(size_t)(kc + r) * 128 + c4];
        }
        __syncthreads();
        #pragma unroll
        for (int k4 = 0; k4 < 64; k4 += 4) {
            float4 a[4];
            #pragma unroll
            for (int i = 0; i < 4; ++i) a[i] = *(const float4*)&xs[r16 * 4 + i][k4];
            #pragma unroll
            for (int kk = 0; kk < 4; ++kk) {
                float4 b0 = *(const float4*)&ms[k4 + kk][c16 * 8];
                float4 b1 = *(const float4*)&ms[k4 + kk][c16 * 8 + 4];
                float bb[8] = {b0.x, b0.y, b0.z, b0.w, b1.x, b1.y, b1.z, b1.w};
                #pragma unroll
                for (int i = 0; i < 4; ++i) {
                    float av = (kk == 0) ? a[i].x : (kk == 1) ? a[i].y : (kk == 2) ? a[i].z : a[i].w;
                    #pragma unroll
                    for (int j = 0; j < 8; ++j) acc[i][j] += av * bb[j];
                }
            }
        }
    }
    #pragma unroll
    for (int i = 0; i < 4; ++i) {
        int grow = row0 + r16 * 4 + i;
        if (grow >= n) continue;
        float norm = rsqrtf(fmaxf((float)degs[grow], 1.0f));
        float4 o0, o1;
        float* po0 = &o0.x; float* po1 = &o1.x;
        #pragma unroll
        for (int j = 0; j < 4; ++j) {
            float v0 = acc[i][j], v1 = acc[i][j + 4];
            if (cvec) { v0 += cvec[c16 * 8 + j]; v1 += cvec[c16 * 8 + 4 + j]; }
            po0[j] = v0 * norm; po1[j] = v1 * norm;
        }
        *(float4*)&T[(size_t)grow * 128 + c16 * 8]     = o0;
        *(float4*)&T[(size_t)grow * 128 + c16 * 8 + 4] = o1;
    }
}

// ---------------------------------------------------------------- aggregate: out[n] = relu(norm_dst * sum_{e} T[csr[e]] + bias)
__global__ __launch_bounds__(256) void aggregate(
    const float* __restrict__ T, const int* __restrict__ rowptr,
    const int* __restrict__ csr, const int* __restrict__ deg_in,
    const float* __restrict__ bias, float* __restrict__ out, int n)
{
    int wave = threadIdx.x >> 6;
    int lane = threadIdx.x & 63;
    int node = blockIdx.x * 4 + wave;
    if (node >= n) return;
    int beg = rowptr[node], end = rowptr[node + 1];
    float2 acc = make_float2(0.f, 0.f);
    int e = beg;
    for (; e + 3 < end; e += 4) {
        int s0 = csr[e], s1 = csr[e + 1], s2 = csr[e + 2], s3 = csr[e + 3];
        float2 v0 = *(const float2*)&T[(size_t)s0 * 128 + lane * 2];
        float2 v1 = *(const float2*)&T[(size_t)s1 * 128 + lane * 2];
        float2 v2 = *(const float2*)&T[(size_t)s2 * 128 + lane * 2];
        float2 v3 = *(const float2*)&T[(size_t)s3 * 128 + lane * 2];
        acc.x += (v0.x + v1.x) + (v2.x + v3.x);
        acc.y += (v0.y + v1.y) + (v2.y + v3.y);
    }
    for (; e < end; ++e) {
        int s0 = csr[e];
        float2 v0 = *(const float2*)&T[(size_t)s0 * 128 + lane * 2];
        acc.x += v0.x; acc.y += v0.y;
    }
    float norm = rsqrtf(fmaxf((float)deg_in[node], 1.0f));
    float2 bv = *(const float2*)&bias[lane * 2];
    float ox = fmaxf(acc.x * norm + bv.x, 0.f);
    float oy = fmaxf(acc.y * norm + bv.y, 0.f);
    *(float2*)&out[(size_t)node * 128 + lane * 2] = make_float2(ox, oy);
}

// ---------------------------------------------------------------- launch
extern "C" void kernel_launch(void* const* d_in, const int* in_sizes, int n_in,
                              void* d_out, int out_size, void* d_ws, size_t ws_size,
                              hipStream_t stream) {
    const float* x   = (const float*)d_in[0];
    const float* We  = (const float*)d_in[1];
    const float* be  = (const float*)d_in[2];
    const float* W1  = (const float*)d_in[3];
    const float* b1  = (const float*)d_in[4];
    const float* W2  = (const float*)d_in[5];
    const float* b2  = (const float*)d_in[6];
    const int* src0  = (const int*)d_in[7];
    const int* dst0  = (const int*)d_in[8];
    const int* src1  = (const int*)d_in[9];
    const int* dst1  = (const int*)d_in[10];
    float* out = (float*)d_out;

    const int n = in_sizes[0] / 256;   // 100000
    const int E = in_sizes[7];         // 1600000

    char* p = (char*)d_ws;
    auto carve = [&](size_t bytes) -> void* {
        void* r = (void*)p;
        p += (bytes + 511) & ~(size_t)511;
        return r;
    };
    float* t      = (float*)carve((size_t)n * HID * 4);
    float* h1     = (float*)carve((size_t)n * HID * 4);
    float* M      = (float*)carve(256 * HID * 4);
    float* cv     = (float*)carve(HID * 4);
    int*   degblk = (int*)carve((size_t)4 * n * 4);
    int*   dout0  = degblk;
    int*   din0   = degblk + n;
    int*   dout1  = degblk + 2 * n;
    int*   din1   = degblk + 3 * n;
    int*   rowptr = (int*)carve(((size_t)n + 1) * 4);
    int*   cursor = (int*)carve((size_t)n * 4);
    int*   csr    = (int*)carve((size_t)E * 4);
    int*   partials = (int*)carve(4096);

    const int nbScan = (n + 1023) / 1024;          // 98
    const int gEdge  = (E + 255) / 256;            // 6250
    const int gGemm  = (n + 63) / 64;              // 1563
    const int gAgg   = (n + 3) / 4;                // 25000
    const int gScanC = (n + 1 + 255) / 256;

    // zero degree counters (only state we accumulate into)
    hipMemsetAsync(degblk, 0, (size_t)4 * n * 4, stream);

    degrees_kernel<<<gEdge, 256, 0, stream>>>(src0, dst0, src1, dst1, dout0, din0, dout1, din1, E);
    weight_fuse<<<129, 256, 0, stream>>>(We, be, W1, M, cv);

    // ---- layer 1 ----
    scan_a<<<nbScan, 256, 0, stream>>>(din0, rowptr, partials, n);
    scan_b<<<1, 128, 0, stream>>>(partials, nbScan);
    scan_c<<<gScanC, 256, 0, stream>>>(rowptr, partials, cursor, n, E);
    csr_fill<<<gEdge, 256, 0, stream>>>(src0, dst0, cursor, csr, E);

    gemm_rowscale<256><<<gGemm, 256, 0, stream>>>(x, M, cv, dout0, t, n);
    aggregate<<<gAgg, 256, 0, stream>>>(t, rowptr, csr, din0, b1, h1, n);

    // ---- layer 2 ----
    scan_a<<<nbScan, 256, 0, stream>>>(din1, rowptr, partials, n);
    scan_b<<<1, 128, 0, stream>>>(partials, nbScan);
    scan_c<<<gScanC, 256, 0, stream>>>(rowptr, partials, cursor, n, E);
    csr_fill<<<gEdge, 256, 0, stream>>>(src1, dst1, cursor, csr, E);

    gemm_rowscale<128><<<gGemm, 256, 0, stream>>>(h1, W2, nullptr, dout1, t, n);
    aggregate<<<gAgg, 256, 0, stream>>>(t, rowptr, csr, din1, b2, out, n);
}

// Round 2
// 557.681 us; speedup vs baseline: 1.6727x; 1.6727x over previous
//
#include <hip/hip_runtime.h>

#define HID 128
#define NBUCK 512          // 2^9 buckets, 256 nodes each (391 used for N=100000)
#define BSHIFT 8           // nodes per bucket = 256
#define NB 512             // chunk blocks per pipeline
#define M4 (4 * NBUCK * NB)
#define STAGE_CAP 8192     // >= bucket size +64 sigma; never exceeded for this data

// ---------------------------------------------------------------- P1: per-(bucket, block) counts, LDS histogram, no atomics to global
__global__ __launch_bounds__(256) void bucket_count(
    const int* __restrict__ keys, int* __restrict__ counts, int pipe, int E, int chunk) {
    __shared__ int h[NBUCK];
    int tid = threadIdx.x;
    h[tid] = 0; h[tid + 256] = 0;
    __syncthreads();
    int base = blockIdx.x * chunk;
    int end = min(base + chunk, E);
    for (int i = base + tid; i < end; i += 256)
        atomicAdd(&h[keys[i] >> BSHIFT], 1);
    __syncthreads();
    counts[((pipe << 9) + tid) * NB + blockIdx.x] = h[tid];
    counts[((pipe << 9) + tid + 256) * NB + blockIdx.x] = h[tid + 256];
}

// ---------------------------------------------------------------- scan over M4 elements (in-place), 3 kernels
__global__ __launch_bounds__(256) void scan_a(int* __restrict__ data, int* __restrict__ partials, int m) {
    __shared__ int sdata[256];
    int base = blockIdx.x * 1024;
    int tid = threadIdx.x;
    int v[4]; int s = 0;
    #pragma unroll
    for (int i = 0; i < 4; ++i) { int idx = base + tid * 4 + i; v[i] = (idx < m) ? data[idx] : 0; s += v[i]; }
    sdata[tid] = s; __syncthreads();
    for (int off = 1; off < 256; off <<= 1) {
        int t = (tid >= off) ? sdata[tid - off] : 0; __syncthreads();
        sdata[tid] += t; __syncthreads();
    }
    int excl = sdata[tid] - s;
    if (tid == 255) partials[blockIdx.x] = sdata[255];
    int run = excl;
    #pragma unroll
    for (int i = 0; i < 4; ++i) { int idx = base + tid * 4 + i; if (idx < m) data[idx] = run; run += v[i]; }
}

__global__ __launch_bounds__(1024) void scan_b(int* __restrict__ partials, int nb) {
    __shared__ int sdata[1024];
    int tid = threadIdx.x;
    int v = (tid < nb) ? partials[tid] : 0;
    sdata[tid] = v; __syncthreads();
    for (int off = 1; off < 1024; off <<= 1) {
        int t = (tid >= off) ? sdata[tid - off] : 0; __syncthreads();
        sdata[tid] += t; __syncthreads();
    }
    if (tid < nb) partials[tid] = sdata[tid] - v;
}

__global__ __launch_bounds__(256) void scan_c(int* __restrict__ data, const int* __restrict__ partials, int m) {
    int i = blockIdx.x * 256 + threadIdx.x;
    if (i < m) data[i] += partials[i >> 10];
}

// ---------------------------------------------------------------- P3: scatter edges into buckets, LDS cursors (no global atomics)
// bucketed[pos] = (keyLocal << 17) | payload   (keyLocal 8b, payload=src 17b)
__global__ __launch_bounds__(256) void bucket_scatter(
    const int* __restrict__ keys, const int* __restrict__ payload,
    const int* __restrict__ scanned, unsigned* __restrict__ bucketed,
    int pipe, int E, int chunk) {
    __shared__ unsigned cur[NBUCK];
    int tid = threadIdx.x;
    int blk = blockIdx.x;
    cur[tid]       = (unsigned)scanned[((pipe << 9) + tid) * NB + blk];
    cur[tid + 256] = (unsigned)scanned[((pipe << 9) + tid + 256) * NB + blk];
    __syncthreads();
    int base = blk * chunk;
    int end = min(base + chunk, E);
    for (int i = base + tid; i < end; i += 256) {
        int k = keys[i];
        int b = k >> BSHIFT;
        unsigned pay = payload ? (unsigned)payload[i] : 0u;
        unsigned pos = atomicAdd(&cur[b], 1u);
        bucketed[pos] = ((unsigned)(k & 255) << 17) | pay;
    }
}

// ---------------------------------------------------------------- P4: per bucket, exact degrees + rowptr + in-bucket CSR
// pipes: 0 = dst0 (csr0/rowptr0), 1 = dst1 (csr1/rowptr1), 2 = src0 (dout0), 3 = src1 (dout1)
// csr_l overlays the bucketed region of pipe l (block stages its whole range into LDS before writing).
__global__ __launch_bounds__(256) void bucket_finalize(
    unsigned* __restrict__ bucketed, const int* __restrict__ scanned,
    int* __restrict__ rowptr0, int* __restrict__ rowptr1,
    int* __restrict__ dout0, int* __restrict__ dout1, int n, int E) {
    __shared__ unsigned stage[STAGE_CAP];
    __shared__ int cnt[256];
    __shared__ int sd[256];
    __shared__ int excl[256];
    __shared__ int cur[256];
    int tid = threadIdx.x;
    int g = blockIdx.x;            // 0..2047
    int p = g >> 9;
    int b = g & 511;
    int start = scanned[g * NB];
    int end = (g == 4 * NBUCK - 1) ? 4 * E : scanned[(g + 1) * NB];
    if (end - start > STAGE_CAP) end = start + STAGE_CAP;   // unreachable safety clamp
    int len = end - start;
    int node0 = b << BSHIFT;

    cnt[tid] = 0;
    __syncthreads();
    for (int i = tid; i < len; i += 256) {
        unsigned v = bucketed[start + i];
        stage[i] = v;
        atomicAdd(&cnt[v >> 17], 1);
    }
    __syncthreads();

    if (p >= 2) {                   // src-keyed: out-degrees only
        int* dout = (p == 2) ? dout0 : dout1;
        int node = node0 + tid;
        if (node < n) dout[node] = cnt[tid];
        return;
    }

    // dst-keyed: exclusive scan of cnt -> excl
    int v = cnt[tid];
    sd[tid] = v;
    __syncthreads();
    for (int off = 1; off < 256; off <<= 1) {
        int t = (tid >= off) ? sd[tid - off] : 0; __syncthreads();
        sd[tid] += t; __syncthreads();
    }
    excl[tid] = sd[tid] - v;
    cur[tid] = 0;
    __syncthreads();

    int startLocal = start - p * E;
    int* rp = (p == 0) ? rowptr0 : rowptr1;
    int node = node0 + tid;
    if (node < n) rp[node] = startLocal + excl[tid];
    if (b == NBUCK - 1 && tid == 0) rp[n] = E;

    int* csr = (int*)bucketed + p * E;   // overlay: this block writes only its own staged range
    for (int i = tid; i < len; i += 256) {
        unsigned w = stage[i];
        int nl = (int)(w >> 17);
        int pos = startLocal + excl[nl] + atomicAdd(&cur[nl], 1);
        csr[pos] = (int)(w & 0x1FFFFu);
    }
}

// ---------------------------------------------------------------- fused weights: M = We@W1, cv = be@W1
__global__ __launch_bounds__(256) void weight_fuse(
    const float* __restrict__ We, const float* __restrict__ be,
    const float* __restrict__ W1, float* __restrict__ M, float* __restrict__ cv) {
    __shared__ float w1[128][128];
    int tid = threadIdx.x;
    #pragma unroll
    for (int it = 0; it < 16; ++it) {
        int s = tid + it * 256;
        int r = s >> 5, c4 = (s & 31) << 2;
        *(float4*)&w1[r][c4] = *(const float4*)&W1[r * 128 + c4];
    }
    __syncthreads();
    int j = tid & 127;
    int half = tid >> 7;
    if (blockIdx.x == 128) {
        if (half) return;
        float sum = 0.f;
        for (int k = 0; k < 128; ++k) sum += be[k] * w1[k][j];
        cv[j] = sum;
        return;
    }
    int i = blockIdx.x * 2 + half;
    const float* arow = &We[i * 128];
    float sum = 0.f;
    for (int k = 0; k < 128; ++k) sum += arow[k] * w1[k][j];
    M[i * 128 + j] = sum;
}

// ---------------------------------------------------------------- GEMM: T = (X @ M + cv) * rsqrt(max(deg,1)) per row
template <int K>
__global__ __launch_bounds__(256) void gemm_rowscale(
    const float* __restrict__ X, const float* __restrict__ M,
    const float* __restrict__ cvec, const int* __restrict__ degs,
    float* __restrict__ T, int n) {
    __shared__ float xs[64][68];
    __shared__ float ms[64][128];
    const int tid = threadIdx.x;
    const int c16 = tid & 15;
    const int r16 = tid >> 4;
    const int row0 = blockIdx.x * 64;

    float acc[4][8];
    #pragma unroll
    for (int i = 0; i < 4; ++i)
        #pragma unroll
        for (int j = 0; j < 8; ++j) acc[i][j] = 0.f;

    for (int kc = 0; kc < K; kc += 64) {
        __syncthreads();
        #pragma unroll
        for (int it = 0; it < 4; ++it) {
            int s = tid + it * 256;
            int r = s >> 4;
            int k4 = (s & 15) << 2;
            int grow = row0 + r;
            float4 v = make_float4(0.f, 0.f, 0.f, 0.f);
            if (grow < n) v = *(const float4*)&X[(size_t)grow * K + kc + k4];
            *(float4*)&xs[r][k4] = v;
        }
        #pragma unroll
        for (int it = 0; it < 8; ++it) {
            int s = tid + it * 256;
            int r = s >> 5;
            int c4 = (s & 31) << 2;
            *(float4*)&ms[r][c4] = *(const float4*)&M[(size_t)(kc + r) * 128 + c4];
        }
        __syncthreads();
        #pragma unroll
        for (int k4 = 0; k4 < 64; k4 += 4) {
            float4 a[4];
            #pragma unroll
            for (int i = 0; i < 4; ++i) a[i] = *(const float4*)&xs[r16 * 4 + i][k4];
            #pragma unroll
            for (int kk = 0; kk < 4; ++kk) {
                float4 b0 = *(const float4*)&ms[k4 + kk][c16 * 8];
                float4 b1 = *(const float4*)&ms[k4 + kk][c16 * 8 + 4];
                float bb[8] = {b0.x, b0.y, b0.z, b0.w, b1.x, b1.y, b1.z, b1.w};
                #pragma unroll
                for (int i = 0; i < 4; ++i) {
                    float av = (kk == 0) ? a[i].x : (kk == 1) ? a[i].y : (kk == 2) ? a[i].z : a[i].w;
                    #pragma unroll
                    for (int j = 0; j < 8; ++j) acc[i][j] += av * bb[j];
                }
            }
        }
    }
    #pragma unroll
    for (int i = 0; i < 4; ++i) {
        int grow = row0 + r16 * 4 + i;
        if (grow >= n) continue;
        float norm = rsqrtf(fmaxf((float)degs[grow], 1.0f));
        float4 o0, o1;
        float* po0 = &o0.x; float* po1 = &o1.x;
        #pragma unroll
        for (int j = 0; j < 4; ++j) {
            float v0 = acc[i][j], v1 = acc[i][j + 4];
            if (cvec) { v0 += cvec[c16 * 8 + j]; v1 += cvec[c16 * 8 + 4 + j]; }
            po0[j] = v0 * norm; po1[j] = v1 * norm;
        }
        *(float4*)&T[(size_t)grow * 128 + c16 * 8]     = o0;
        *(float4*)&T[(size_t)grow * 128 + c16 * 8 + 4] = o1;
    }
}

// ---------------------------------------------------------------- aggregate: out = relu(norm_dst * sum T[csr[e]] + bias)
__global__ __launch_bounds__(256) void aggregate(
    const float* __restrict__ T, const int* __restrict__ rowptr,
    const int* __restrict__ csr, const float* __restrict__ bias,
    float* __restrict__ out, int n) {
    int wave = threadIdx.x >> 6;
    int lane = threadIdx.x & 63;
    int node = blockIdx.x * 4 + wave;
    if (node >= n) return;
    int beg = rowptr[node], end = rowptr[node + 1];
    float2 acc = make_float2(0.f, 0.f);
    int e = beg;
    for (; e + 3 < end; e += 4) {
        int s0 = csr[e], s1 = csr[e + 1], s2 = csr[e + 2], s3 = csr[e + 3];
        float2 v0 = *(const float2*)&T[(size_t)s0 * 128 + lane * 2];
        float2 v1 = *(const float2*)&T[(size_t)s1 * 128 + lane * 2];
        float2 v2 = *(const float2*)&T[(size_t)s2 * 128 + lane * 2];
        float2 v3 = *(const float2*)&T[(size_t)s3 * 128 + lane * 2];
        acc.x += (v0.x + v1.x) + (v2.x + v3.x);
        acc.y += (v0.y + v1.y) + (v2.y + v3.y);
    }
    for (; e < end; ++e) {
        int s0 = csr[e];
        float2 v0 = *(const float2*)&T[(size_t)s0 * 128 + lane * 2];
        acc.x += v0.x; acc.y += v0.y;
    }
    float norm = rsqrtf(fmaxf((float)(end - beg), 1.0f));
    float2 bv = *(const float2*)&bias[lane * 2];
    float ox = fmaxf(acc.x * norm + bv.x, 0.f);
    float oy = fmaxf(acc.y * norm + bv.y, 0.f);
    *(float2*)&out[(size_t)node * 128 + lane * 2] = make_float2(ox, oy);
}

// ---------------------------------------------------------------- launch
extern "C" void kernel_launch(void* const* d_in, const int* in_sizes, int n_in,
                              void* d_out, int out_size, void* d_ws, size_t ws_size,
                              hipStream_t stream) {
    const float* x   = (const float*)d_in[0];
    const float* We  = (const float*)d_in[1];
    const float* be  = (const float*)d_in[2];
    const float* W1  = (const float*)d_in[3];
    const float* b1  = (const float*)d_in[4];
    const float* W2  = (const float*)d_in[5];
    const float* b2  = (const float*)d_in[6];
    const int* src0  = (const int*)d_in[7];
    const int* dst0  = (const int*)d_in[8];
    const int* src1  = (const int*)d_in[9];
    const int* dst1  = (const int*)d_in[10];
    float* out = (float*)d_out;

    const int n = in_sizes[0] / 256;   // 100000
    const int E = in_sizes[7];         // 1600000
    const int chunk = (E + NB - 1) / NB;

    char* p = (char*)d_ws;
    auto carve = [&](size_t bytes) -> void* {
        void* r = (void*)p;
        p += (bytes + 511) & ~(size_t)511;
        return r;
    };
    float*    t        = (float*)carve((size_t)n * HID * 4);
    unsigned* bucketed = (unsigned*)carve((size_t)4 * E * 4);
    int*      counts   = (int*)carve((size_t)M4 * 4);
    int*      partials = (int*)carve(1024 * 4);
    int*      rowptr0  = (int*)carve(((size_t)n + 1) * 4);
    int*      rowptr1  = (int*)carve(((size_t)n + 1) * 4);
    int*      dout0    = (int*)carve((size_t)n * 4);
    int*      dout1    = (int*)carve((size_t)n * 4);
    float*    M        = (float*)carve(256 * HID * 4);
    float*    cv       = (float*)carve(HID * 4);

    int* csr0 = (int*)bucketed;          // overlays pipe-0 region (safe: P4 stages before writing)
    int* csr1 = (int*)bucketed + E;      // overlays pipe-1 region
    float* h1 = out;                     // layer-1 activations live in d_out until consumed by gemm2

    const int gGemm = (n + 63) / 64;
    const int gAgg  = (n + 3) / 4;
    const int gScanA = (M4 + 1023) / 1024;   // 1024
    const int gScanC = (M4 + 255) / 256;

    // --- graph build (zero global atomics) ---
    bucket_count<<<NB, 256, 0, stream>>>(dst0, counts, 0, E, chunk);
    bucket_count<<<NB, 256, 0, stream>>>(dst1, counts, 1, E, chunk);
    bucket_count<<<NB, 256, 0, stream>>>(src0, counts, 2, E, chunk);
    bucket_count<<<NB, 256, 0, stream>>>(src1, counts, 3, E, chunk);
    scan_a<<<gScanA, 256, 0, stream>>>(counts, partials, M4);
    scan_b<<<1, 1024, 0, stream>>>(partials, gScanA);
    scan_c<<<gScanC, 256, 0, stream>>>(counts, partials, M4);
    bucket_scatter<<<NB, 256, 0, stream>>>(dst0, src0, counts, bucketed, 0, E, chunk);
    bucket_scatter<<<NB, 256, 0, stream>>>(dst1, src1, counts, bucketed, 1, E, chunk);
    bucket_scatter<<<NB, 256, 0, stream>>>(src0, nullptr, counts, bucketed, 2, E, chunk);
    bucket_scatter<<<NB, 256, 0, stream>>>(src1, nullptr, counts, bucketed, 3, E, chunk);
    bucket_finalize<<<4 * NBUCK, 256, 0, stream>>>(bucketed, counts, rowptr0, rowptr1, dout0, dout1, n, E);

    // --- network ---
    weight_fuse<<<129, 256, 0, stream>>>(We, be, W1, M, cv);
    gemm_rowscale<256><<<gGemm, 256, 0, stream>>>(x, M, cv, dout0, t, n);
    aggregate<<<gAgg, 256, 0, stream>>>(t, rowptr0, csr0, b1, h1, n);
    gemm_rowscale<128><<<gGemm, 256, 0, stream>>>(h1, W2, nullptr, dout1, t, n);
    aggregate<<<gAgg, 256, 0, stream>>>(t, rowptr1, csr1, b2, out, n);
}

// Round 3
// 458.365 us; speedup vs baseline: 2.0351x; 1.2167x over previous
//
#include <hip/hip_runtime.h>

#define HID 128
#define NBUCK 512          // 2^9 buckets, 256 nodes each (391 used for N=100000)
#define BSHIFT 8           // nodes per bucket = 256
#define NB 512             // chunk blocks per pipeline
#define M4 (4 * NBUCK * NB)
#define STAGE_CAP 8192     // >= bucket size +64 sigma; never exceeded for this data

typedef __attribute__((ext_vector_type(8))) short bf16x8;
typedef __attribute__((ext_vector_type(4))) float f32x4;

__device__ __forceinline__ unsigned short f2bf(float f) {
    union { float f; unsigned u; } v; v.f = f;
    unsigned r = v.u + 0x7fff + ((v.u >> 16) & 1);   // RTN-even
    return (unsigned short)(r >> 16);
}
__device__ __forceinline__ float bf2f(unsigned short b) {
    union { float f; unsigned u; } v; v.u = ((unsigned)b) << 16;
    return v.f;
}

// ---------------------------------------------------------------- P1: per-(bucket, block) counts
__global__ __launch_bounds__(256) void bucket_count(
    const int* __restrict__ keys, int* __restrict__ counts, int pipe, int E, int chunk) {
    __shared__ int h[NBUCK];
    int tid = threadIdx.x;
    h[tid] = 0; h[tid + 256] = 0;
    __syncthreads();
    int base = blockIdx.x * chunk;
    int end = min(base + chunk, E);
    for (int i = base + tid; i < end; i += 256)
        atomicAdd(&h[keys[i] >> BSHIFT], 1);
    __syncthreads();
    counts[((pipe << 9) + tid) * NB + blockIdx.x] = h[tid];
    counts[((pipe << 9) + tid + 256) * NB + blockIdx.x] = h[tid + 256];
}

// ---------------------------------------------------------------- scan (3 kernels)
__global__ __launch_bounds__(256) void scan_a(int* __restrict__ data, int* __restrict__ partials, int m) {
    __shared__ int sdata[256];
    int base = blockIdx.x * 1024;
    int tid = threadIdx.x;
    int v[4]; int s = 0;
    #pragma unroll
    for (int i = 0; i < 4; ++i) { int idx = base + tid * 4 + i; v[i] = (idx < m) ? data[idx] : 0; s += v[i]; }
    sdata[tid] = s; __syncthreads();
    for (int off = 1; off < 256; off <<= 1) {
        int t = (tid >= off) ? sdata[tid - off] : 0; __syncthreads();
        sdata[tid] += t; __syncthreads();
    }
    int excl = sdata[tid] - s;
    if (tid == 255) partials[blockIdx.x] = sdata[255];
    int run = excl;
    #pragma unroll
    for (int i = 0; i < 4; ++i) { int idx = base + tid * 4 + i; if (idx < m) data[idx] = run; run += v[i]; }
}

__global__ __launch_bounds__(1024) void scan_b(int* __restrict__ partials, int nb) {
    __shared__ int sdata[1024];
    int tid = threadIdx.x;
    int v = (tid < nb) ? partials[tid] : 0;
    sdata[tid] = v; __syncthreads();
    for (int off = 1; off < 1024; off <<= 1) {
        int t = (tid >= off) ? sdata[tid - off] : 0; __syncthreads();
        sdata[tid] += t; __syncthreads();
    }
    if (tid < nb) partials[tid] = sdata[tid] - v;
}

__global__ __launch_bounds__(256) void scan_c(int* __restrict__ data, const int* __restrict__ partials, int m) {
    int i = blockIdx.x * 256 + threadIdx.x;
    if (i < m) data[i] += partials[i >> 10];
}

// ---------------------------------------------------------------- P3: scatter edges into buckets
__global__ __launch_bounds__(256) void bucket_scatter(
    const int* __restrict__ keys, const int* __restrict__ payload,
    const int* __restrict__ scanned, unsigned* __restrict__ bucketed,
    int pipe, int E, int chunk) {
    __shared__ unsigned cur[NBUCK];
    int tid = threadIdx.x;
    int blk = blockIdx.x;
    cur[tid]       = (unsigned)scanned[((pipe << 9) + tid) * NB + blk];
    cur[tid + 256] = (unsigned)scanned[((pipe << 9) + tid + 256) * NB + blk];
    __syncthreads();
    int base = blk * chunk;
    int end = min(base + chunk, E);
    for (int i = base + tid; i < end; i += 256) {
        int k = keys[i];
        int b = k >> BSHIFT;
        unsigned pay = payload ? (unsigned)payload[i] : 0u;
        unsigned pos = atomicAdd(&cur[b], 1u);
        bucketed[pos] = ((unsigned)(k & 255) << 17) | pay;
    }
}

// ---------------------------------------------------------------- P4: per bucket, degrees + rowptr + in-bucket CSR
__global__ __launch_bounds__(256) void bucket_finalize(
    unsigned* __restrict__ bucketed, const int* __restrict__ scanned,
    int* __restrict__ rowptr0, int* __restrict__ rowptr1,
    int* __restrict__ dout0, int* __restrict__ dout1, int n, int E) {
    __shared__ unsigned stage[STAGE_CAP];
    __shared__ int cnt[256];
    __shared__ int sd[256];
    __shared__ int excl[256];
    __shared__ int cur[256];
    int tid = threadIdx.x;
    int g = blockIdx.x;
    int p = g >> 9;
    int b = g & 511;
    int start = scanned[g * NB];
    int end = (g == 4 * NBUCK - 1) ? 4 * E : scanned[(g + 1) * NB];
    if (end - start > STAGE_CAP) end = start + STAGE_CAP;
    int len = end - start;
    int node0 = b << BSHIFT;

    cnt[tid] = 0;
    __syncthreads();
    for (int i = tid; i < len; i += 256) {
        unsigned v = bucketed[start + i];
        stage[i] = v;
        atomicAdd(&cnt[v >> 17], 1);
    }
    __syncthreads();

    if (p >= 2) {
        int* dout = (p == 2) ? dout0 : dout1;
        int node = node0 + tid;
        if (node < n) dout[node] = cnt[tid];
        return;
    }

    int v = cnt[tid];
    sd[tid] = v;
    __syncthreads();
    for (int off = 1; off < 256; off <<= 1) {
        int t = (tid >= off) ? sd[tid - off] : 0; __syncthreads();
        sd[tid] += t; __syncthreads();
    }
    excl[tid] = sd[tid] - v;
    cur[tid] = 0;
    __syncthreads();

    int startLocal = start - p * E;
    int* rp = (p == 0) ? rowptr0 : rowptr1;
    int node = node0 + tid;
    if (node < n) rp[node] = startLocal + excl[tid];
    if (b == NBUCK - 1 && tid == 0) rp[n] = E;

    int* csr = (int*)bucketed + p * E;
    for (int i = tid; i < len; i += 256) {
        unsigned w = stage[i];
        int nl = (int)(w >> 17);
        int pos = startLocal + excl[nl] + atomicAdd(&cur[nl], 1);
        csr[pos] = (int)(w & 0x1FFFFu);
    }
}

// ---------------------------------------------------------------- swizzled B-fragment index for mfma_f32_16x16x32_bf16
// B[k][col]: lane = (k>>3 & 3)*16 + (col&15), j = k&7, s = k>>5, c = col>>4
__device__ __forceinline__ size_t bswz_idx(int k, int col) {
    int s = k >> 5, lh = (k >> 3) & 3, j = k & 7;
    int c = col >> 4, lc = col & 15;
    return ((((size_t)s * 8 + c) * 64 + (lh * 16 + lc)) * 8 + j);
}

// ---------------------------------------------------------------- weight_fuse: M = We@W1 -> swizzled split bf16; cv = be@W1 (fp32)
__global__ __launch_bounds__(256) void weight_fuse(
    const float* __restrict__ We, const float* __restrict__ be,
    const float* __restrict__ W1,
    unsigned short* __restrict__ B1h, unsigned short* __restrict__ B1l,
    float* __restrict__ cv) {
    __shared__ float w1[128][128];
    int tid = threadIdx.x;
    #pragma unroll
    for (int it = 0; it < 16; ++it) {
        int s = tid + it * 256;
        int r = s >> 5, c4 = (s & 31) << 2;
        *(float4*)&w1[r][c4] = *(const float4*)&W1[r * 128 + c4];
    }
    __syncthreads();
    int j = tid & 127;
    int half = tid >> 7;
    if (blockIdx.x == 128) {
        if (half) return;
        float sum = 0.f;
        for (int k = 0; k < 128; ++k) sum += be[k] * w1[k][j];
        cv[j] = sum;
        return;
    }
    int i = blockIdx.x * 2 + half;
    const float* arow = &We[i * 128];
    float sum = 0.f;
    for (int k = 0; k < 128; ++k) sum += arow[k] * w1[k][j];
    unsigned short h = f2bf(sum);
    unsigned short l = f2bf(sum - bf2f(h));
    size_t o = bswz_idx(i, j);
    B1h[o] = h; B1l[o] = l;
}

// ---------------------------------------------------------------- split+swizzle a [K,128] fp32 matrix into MFMA-B bf16 hi/lo
__global__ __launch_bounds__(256) void swizzle_split(
    const float* __restrict__ W, unsigned short* __restrict__ Bh,
    unsigned short* __restrict__ Bl, int K) {
    int idx = blockIdx.x * 256 + threadIdx.x;
    if (idx >= K * 128) return;
    int k = idx >> 7, col = idx & 127;
    float v = W[idx];
    unsigned short h = f2bf(v);
    unsigned short l = f2bf(v - bf2f(h));
    size_t o = bswz_idx(k, col);
    Bh[o] = h; Bl[o] = l;
}

// ---------------------------------------------------------------- MFMA GEMM: T = (X @ W + cv) * rsqrt(max(deg,1))
// X:[n,K] fp32, W pre-swizzled bf16 hi/lo. Split-precision: Ah*Bh + Ah*Bl + Al*Bh.
// Block = 4 waves, 128 rows x 128 cols. Wave w: rows [blk*128 + w*32, +32).
template <int K>
__global__ __launch_bounds__(256) void gemm_mfma(
    const float* __restrict__ X,
    const unsigned short* __restrict__ Bh, const unsigned short* __restrict__ Bl,
    const float* __restrict__ cvec, const int* __restrict__ degs,
    float* __restrict__ T, int n) {
    const int tid = threadIdx.x;
    const int wave = tid >> 6;
    const int lane = tid & 63;
    const int lr = lane & 15;     // A-row / B-col within 16-tile
    const int lk = lane >> 4;     // k-group (0..3)
    const int row0 = blockIdx.x * 128 + wave * 32;

    f32x4 acc[2][8];
    #pragma unroll
    for (int rt = 0; rt < 2; ++rt)
        #pragma unroll
        for (int c = 0; c < 8; ++c) acc[rt][c] = (f32x4)0.f;

    const int r0 = row0 + lr;
    const int r1 = row0 + 16 + lr;
    const bool v0 = r0 < n, v1 = r1 < n;
    const float* px0 = X + (size_t)r0 * K + lk * 8;
    const float* px1 = X + (size_t)r1 * K + lk * 8;
    const bf16x8* pBh = (const bf16x8*)Bh;
    const bf16x8* pBl = (const bf16x8*)Bl;

    for (int s = 0; s < K / 32; ++s) {
        float a0[8], a1[8];
        #pragma unroll
        for (int j = 0; j < 8; ++j) { a0[j] = 0.f; a1[j] = 0.f; }
        if (v0) {
            *(float4*)&a0[0] = *(const float4*)(px0 + s * 32);
            *(float4*)&a0[4] = *(const float4*)(px0 + s * 32 + 4);
        }
        if (v1) {
            *(float4*)&a1[0] = *(const float4*)(px1 + s * 32);
            *(float4*)&a1[4] = *(const float4*)(px1 + s * 32 + 4);
        }
        bf16x8 ah0, al0, ah1, al1;
        #pragma unroll
        for (int j = 0; j < 8; ++j) {
            unsigned short h0 = f2bf(a0[j]);
            ah0[j] = (short)h0;
            al0[j] = (short)f2bf(a0[j] - bf2f(h0));
            unsigned short h1 = f2bf(a1[j]);
            ah1[j] = (short)h1;
            al1[j] = (short)f2bf(a1[j] - bf2f(h1));
        }
        const int fbase = s * 8 * 64 + lane;
        #pragma unroll
        for (int c = 0; c < 8; ++c) {
            bf16x8 bh = pBh[fbase + c * 64];
            bf16x8 bl = pBl[fbase + c * 64];
            acc[0][c] = __builtin_amdgcn_mfma_f32_16x16x32_bf16(ah0, bh, acc[0][c], 0, 0, 0);
            acc[0][c] = __builtin_amdgcn_mfma_f32_16x16x32_bf16(ah0, bl, acc[0][c], 0, 0, 0);
            acc[0][c] = __builtin_amdgcn_mfma_f32_16x16x32_bf16(al0, bh, acc[0][c], 0, 0, 0);
            acc[1][c] = __builtin_amdgcn_mfma_f32_16x16x32_bf16(ah1, bh, acc[1][c], 0, 0, 0);
            acc[1][c] = __builtin_amdgcn_mfma_f32_16x16x32_bf16(ah1, bl, acc[1][c], 0, 0, 0);
            acc[1][c] = __builtin_amdgcn_mfma_f32_16x16x32_bf16(al1, bh, acc[1][c], 0, 0, 0);
        }
    }

    // C/D layout: col = lane&15, row = (lane>>4)*4 + reg
    #pragma unroll
    for (int rt = 0; rt < 2; ++rt) {
        #pragma unroll
        for (int r = 0; r < 4; ++r) {
            int grow = row0 + rt * 16 + lk * 4 + r;
            if (grow >= n) continue;
            float norm = rsqrtf(fmaxf((float)degs[grow], 1.0f));
            #pragma unroll
            for (int c = 0; c < 8; ++c) {
                float v = acc[rt][c][r];
                if (cvec) v += cvec[c * 16 + lr];
                T[(size_t)grow * 128 + c * 16 + lr] = v * norm;
            }
        }
    }
}

// ---------------------------------------------------------------- aggregate: out = relu(norm_dst * sum T[csr[e]] + bias)
__global__ __launch_bounds__(256) void aggregate(
    const float* __restrict__ T, const int* __restrict__ rowptr,
    const int* __restrict__ csr, const float* __restrict__ bias,
    float* __restrict__ out, int n) {
    int wave = threadIdx.x >> 6;
    int lane = threadIdx.x & 63;
    int node = blockIdx.x * 4 + wave;
    if (node >= n) return;
    int beg = rowptr[node], end = rowptr[node + 1];
    float2 acc = make_float2(0.f, 0.f);
    int e = beg;
    for (; e + 3 < end; e += 4) {
        int s0 = csr[e], s1 = csr[e + 1], s2 = csr[e + 2], s3 = csr[e + 3];
        float2 v0 = *(const float2*)&T[(size_t)s0 * 128 + lane * 2];
        float2 v1 = *(const float2*)&T[(size_t)s1 * 128 + lane * 2];
        float2 v2 = *(const float2*)&T[(size_t)s2 * 128 + lane * 2];
        float2 v3 = *(const float2*)&T[(size_t)s3 * 128 + lane * 2];
        acc.x += (v0.x + v1.x) + (v2.x + v3.x);
        acc.y += (v0.y + v1.y) + (v2.y + v3.y);
    }
    for (; e < end; ++e) {
        int s0 = csr[e];
        float2 v0 = *(const float2*)&T[(size_t)s0 * 128 + lane * 2];
        acc.x += v0.x; acc.y += v0.y;
    }
    float norm = rsqrtf(fmaxf((float)(end - beg), 1.0f));
    float2 bv = *(const float2*)&bias[lane * 2];
    float ox = fmaxf(acc.x * norm + bv.x, 0.f);
    float oy = fmaxf(acc.y * norm + bv.y, 0.f);
    *(float2*)&out[(size_t)node * 128 + lane * 2] = make_float2(ox, oy);
}

// ---------------------------------------------------------------- launch
extern "C" void kernel_launch(void* const* d_in, const int* in_sizes, int n_in,
                              void* d_out, int out_size, void* d_ws, size_t ws_size,
                              hipStream_t stream) {
    const float* x   = (const float*)d_in[0];
    const float* We  = (const float*)d_in[1];
    const float* be  = (const float*)d_in[2];
    const float* W1  = (const float*)d_in[3];
    const float* b1  = (const float*)d_in[4];
    const float* W2  = (const float*)d_in[5];
    const float* b2  = (const float*)d_in[6];
    const int* src0  = (const int*)d_in[7];
    const int* dst0  = (const int*)d_in[8];
    const int* src1  = (const int*)d_in[9];
    const int* dst1  = (const int*)d_in[10];
    float* out = (float*)d_out;

    const int n = in_sizes[0] / 256;   // 100000
    const int E = in_sizes[7];         // 1600000
    const int chunk = (E + NB - 1) / NB;

    char* p = (char*)d_ws;
    auto carve = [&](size_t bytes) -> void* {
        void* r = (void*)p;
        p += (bytes + 511) & ~(size_t)511;
        return r;
    };
    float*          t        = (float*)carve((size_t)n * HID * 4);
    unsigned*       bucketed = (unsigned*)carve((size_t)4 * E * 4);
    int*            counts   = (int*)carve((size_t)M4 * 4);
    int*            partials = (int*)carve(1024 * 4);
    int*            rowptr0  = (int*)carve(((size_t)n + 1) * 4);
    int*            rowptr1  = (int*)carve(((size_t)n + 1) * 4);
    int*            dout0    = (int*)carve((size_t)n * 4);
    int*            dout1    = (int*)carve((size_t)n * 4);
    unsigned short* B1h      = (unsigned short*)carve(256 * HID * 2);
    unsigned short* B1l      = (unsigned short*)carve(256 * HID * 2);
    unsigned short* B2h      = (unsigned short*)carve(128 * HID * 2);
    unsigned short* B2l      = (unsigned short*)carve(128 * HID * 2);
    float*          cv       = (float*)carve(HID * 4);

    int* csr0 = (int*)bucketed;
    int* csr1 = (int*)bucketed + E;
    float* h1 = out;

    const int gGemm = (n + 127) / 128;
    const int gAgg  = (n + 3) / 4;
    const int gScanA = (M4 + 1023) / 1024;
    const int gScanC = (M4 + 255) / 256;

    // --- graph build (zero global atomics) ---
    bucket_count<<<NB, 256, 0, stream>>>(dst0, counts, 0, E, chunk);
    bucket_count<<<NB, 256, 0, stream>>>(dst1, counts, 1, E, chunk);
    bucket_count<<<NB, 256, 0, stream>>>(src0, counts, 2, E, chunk);
    bucket_count<<<NB, 256, 0, stream>>>(src1, counts, 3, E, chunk);
    scan_a<<<gScanA, 256, 0, stream>>>(counts, partials, M4);
    scan_b<<<1, 1024, 0, stream>>>(partials, gScanA);
    scan_c<<<gScanC, 256, 0, stream>>>(counts, partials, M4);
    bucket_scatter<<<NB, 256, 0, stream>>>(dst0, src0, counts, bucketed, 0, E, chunk);
    bucket_scatter<<<NB, 256, 0, stream>>>(dst1, src1, counts, bucketed, 1, E, chunk);
    bucket_scatter<<<NB, 256, 0, stream>>>(src0, nullptr, counts, bucketed, 2, E, chunk);
    bucket_scatter<<<NB, 256, 0, stream>>>(src1, nullptr, counts, bucketed, 3, E, chunk);
    bucket_finalize<<<4 * NBUCK, 256, 0, stream>>>(bucketed, counts, rowptr0, rowptr1, dout0, dout1, n, E);

    // --- weights ---
    weight_fuse<<<129, 256, 0, stream>>>(We, be, W1, B1h, B1l, cv);
    swizzle_split<<<(128 * 128 + 255) / 256, 256, 0, stream>>>(W2, B2h, B2l, 128);

    // --- network ---
    gemm_mfma<256><<<gGemm, 256, 0, stream>>>(x, B1h, B1l, cv, dout0, t, n);
    aggregate<<<gAgg, 256, 0, stream>>>(t, rowptr0, csr0, b1, h1, n);
    gemm_mfma<128><<<gGemm, 256, 0, stream>>>(h1, B2h, B2l, nullptr, dout1, t, n);
    aggregate<<<gAgg, 256, 0, stream>>>(t, rowptr1, csr1, b2, out, n);
}

// Round 4
// 405.316 us; speedup vs baseline: 2.3015x; 1.1309x over previous
//
#include <hip/hip_runtime.h>

#define HID 128
#define NBUCK 512          // 2^9 buckets, 256 nodes each
#define BSHIFT 8
#define NB 512             // chunk blocks per pipeline
#define M4 (4 * NBUCK * NB)
#define STAGE_CAP 8192

typedef __attribute__((ext_vector_type(8))) short bf16x8;
typedef __attribute__((ext_vector_type(4))) float f32x4;

__device__ __forceinline__ unsigned short f2bf(float f) {   // RNE
    union { float f; unsigned u; } v; v.f = f;
    unsigned r = v.u + 0x7fff + ((v.u >> 16) & 1);
    return (unsigned short)(r >> 16);
}
__device__ __forceinline__ float bf2f(unsigned short b) {
    union { float f; unsigned u; } v; v.u = ((unsigned)b) << 16;
    return v.f;
}

// ---------------------------------------------------------------- split X into bf16 hi/lo planes (truncation split; al compensates)
__global__ __launch_bounds__(256) void split_x(
    const float* __restrict__ X, unsigned short* __restrict__ Xh,
    unsigned short* __restrict__ Xl, long total4) {
    long i = (long)blockIdx.x * 256 + threadIdx.x;
    long stride = (long)gridDim.x * 256;
    for (; i < total4; i += stride) {
        float4 v = ((const float4*)X)[i];
        unsigned b[4] = {__float_as_uint(v.x), __float_as_uint(v.y),
                         __float_as_uint(v.z), __float_as_uint(v.w)};
        float f[4] = {v.x, v.y, v.z, v.w};
        ushort4 h, l;
        unsigned short* ph = &h.x; unsigned short* pl = &l.x;
        #pragma unroll
        for (int j = 0; j < 4; ++j) {
            ph[j] = (unsigned short)(b[j] >> 16);
            float rem = f[j] - __uint_as_float(b[j] & 0xffff0000u);
            pl[j] = (unsigned short)(__float_as_uint(rem) >> 16);
        }
        ((ushort4*)Xh)[i] = h;
        ((ushort4*)Xl)[i] = l;
    }
}

// ---------------------------------------------------------------- P1: all 4 pipes, per-(bucket, block) counts
__global__ __launch_bounds__(256) void bucket_count_all(
    const int* __restrict__ k0, const int* __restrict__ k1,
    const int* __restrict__ k2, const int* __restrict__ k3,
    int* __restrict__ counts, int E, int chunk) {
    __shared__ int h[4][NBUCK];
    int tid = threadIdx.x;
    #pragma unroll
    for (int j = 0; j < 8; ++j) ((int*)h)[tid + j * 256] = 0;
    __syncthreads();
    int base = blockIdx.x * chunk;
    int end = min(base + chunk, E);
    const int* keys[4] = {k0, k1, k2, k3};
    #pragma unroll
    for (int p = 0; p < 4; ++p) {
        const int* kp = keys[p];
        for (int i = base + tid; i < end; i += 256)
            atomicAdd(&h[p][kp[i] >> BSHIFT], 1);
    }
    __syncthreads();
    #pragma unroll
    for (int p = 0; p < 4; ++p) {
        counts[((p << 9) + tid) * NB + blockIdx.x] = h[p][tid];
        counts[((p << 9) + tid + 256) * NB + blockIdx.x] = h[p][tid + 256];
    }
}

// ---------------------------------------------------------------- scan (3 kernels)
__global__ __launch_bounds__(256) void scan_a(int* __restrict__ data, int* __restrict__ partials, int m) {
    __shared__ int sdata[256];
    int base = blockIdx.x * 1024;
    int tid = threadIdx.x;
    int v[4]; int s = 0;
    #pragma unroll
    for (int i = 0; i < 4; ++i) { int idx = base + tid * 4 + i; v[i] = (idx < m) ? data[idx] : 0; s += v[i]; }
    sdata[tid] = s; __syncthreads();
    for (int off = 1; off < 256; off <<= 1) {
        int t = (tid >= off) ? sdata[tid - off] : 0; __syncthreads();
        sdata[tid] += t; __syncthreads();
    }
    int excl = sdata[tid] - s;
    if (tid == 255) partials[blockIdx.x] = sdata[255];
    int run = excl;
    #pragma unroll
    for (int i = 0; i < 4; ++i) { int idx = base + tid * 4 + i; if (idx < m) data[idx] = run; run += v[i]; }
}

__global__ __launch_bounds__(1024) void scan_b(int* __restrict__ partials, int nb) {
    __shared__ int sdata[1024];
    int tid = threadIdx.x;
    int v = (tid < nb) ? partials[tid] : 0;
    sdata[tid] = v; __syncthreads();
    for (int off = 1; off < 1024; off <<= 1) {
        int t = (tid >= off) ? sdata[tid - off] : 0; __syncthreads();
        sdata[tid] += t; __syncthreads();
    }
    if (tid < nb) partials[tid] = sdata[tid] - v;
}

__global__ __launch_bounds__(256) void scan_c(int* __restrict__ data, const int* __restrict__ partials, int m) {
    int i = blockIdx.x * 256 + threadIdx.x;
    if (i < m) data[i] += partials[i >> 10];
}

// ---------------------------------------------------------------- P3: all 4 pipes, scatter into buckets
__global__ __launch_bounds__(256) void bucket_scatter_all(
    const int* __restrict__ k0, const int* __restrict__ k1,
    const int* __restrict__ k2, const int* __restrict__ k3,
    const int* __restrict__ pay0, const int* __restrict__ pay1,
    const int* __restrict__ scanned, unsigned* __restrict__ bucketed,
    int E, int chunk) {
    __shared__ unsigned cur[4][NBUCK];
    int tid = threadIdx.x;
    int blk = blockIdx.x;
    #pragma unroll
    for (int p = 0; p < 4; ++p) {
        cur[p][tid]       = (unsigned)scanned[((p << 9) + tid) * NB + blk];
        cur[p][tid + 256] = (unsigned)scanned[((p << 9) + tid + 256) * NB + blk];
    }
    __syncthreads();
    int base = blk * chunk;
    int end = min(base + chunk, E);
    const int* keys[4] = {k0, k1, k2, k3};
    const int* pays[4] = {pay0, pay1, nullptr, nullptr};
    #pragma unroll
    for (int p = 0; p < 4; ++p) {
        const int* kp = keys[p];
        const int* pp = pays[p];
        for (int i = base + tid; i < end; i += 256) {
            int k = kp[i];
            int b = k >> BSHIFT;
            unsigned pay = pp ? (unsigned)pp[i] : 0u;
            unsigned pos = atomicAdd(&cur[p][b], 1u);
            bucketed[pos] = ((unsigned)(k & 255) << 17) | pay;
        }
    }
}

// ---------------------------------------------------------------- P4: per bucket, degrees + rowptr + in-bucket CSR
__global__ __launch_bounds__(256) void bucket_finalize(
    unsigned* __restrict__ bucketed, const int* __restrict__ scanned,
    int* __restrict__ rowptr0, int* __restrict__ rowptr1,
    int* __restrict__ dout0, int* __restrict__ dout1, int n, int E) {
    __shared__ unsigned stage[STAGE_CAP];
    __shared__ int cnt[256];
    __shared__ int sd[256];
    __shared__ int excl[256];
    __shared__ int cur[256];
    int tid = threadIdx.x;
    int g = blockIdx.x;
    int p = g >> 9;
    int b = g & 511;
    int start = scanned[g * NB];
    int end = (g == 4 * NBUCK - 1) ? 4 * E : scanned[(g + 1) * NB];
    if (end - start > STAGE_CAP) end = start + STAGE_CAP;
    int len = end - start;
    int node0 = b << BSHIFT;

    cnt[tid] = 0;
    __syncthreads();
    if (p < 2) {
        for (int i = tid; i < len; i += 256) {
            unsigned v = bucketed[start + i];
            stage[i] = v;
            atomicAdd(&cnt[v >> 17], 1);
        }
    } else {
        for (int i = tid; i < len; i += 256)
            atomicAdd(&cnt[bucketed[start + i] >> 17], 1);
    }
    __syncthreads();

    if (p >= 2) {
        int* dout = (p == 2) ? dout0 : dout1;
        int node = node0 + tid;
        if (node < n) dout[node] = cnt[tid];
        return;
    }

    int v = cnt[tid];
    sd[tid] = v;
    __syncthreads();
    for (int off = 1; off < 256; off <<= 1) {
        int t = (tid >= off) ? sd[tid - off] : 0; __syncthreads();
        sd[tid] += t; __syncthreads();
    }
    excl[tid] = sd[tid] - v;
    cur[tid] = 0;
    __syncthreads();

    int startLocal = start - p * E;
    int* rp = (p == 0) ? rowptr0 : rowptr1;
    int node = node0 + tid;
    if (node < n) rp[node] = startLocal + excl[tid];
    if (b == NBUCK - 1 && tid == 0) rp[n] = E;

    int* csr = (int*)bucketed + p * E;
    for (int i = tid; i < len; i += 256) {
        unsigned w = stage[i];
        int nl = (int)(w >> 17);
        int pos = startLocal + excl[nl] + atomicAdd(&cur[nl], 1);
        csr[pos] = (int)(w & 0x1FFFFu);
    }
}

// ---------------------------------------------------------------- swizzled B-fragment index for mfma_f32_16x16x32_bf16
__device__ __forceinline__ size_t bswz_idx(int k, int col) {
    int s = k >> 5, lh = (k >> 3) & 3, j = k & 7;
    int c = col >> 4, lc = col & 15;
    return ((((size_t)s * 8 + c) * 64 + (lh * 16 + lc)) * 8 + j);
}

// ---------------------------------------------------------------- weight_fuse: M = We@W1 -> swizzled split bf16; cv = be@W1
__global__ __launch_bounds__(256) void weight_fuse(
    const float* __restrict__ We, const float* __restrict__ be,
    const float* __restrict__ W1,
    unsigned short* __restrict__ B1h, unsigned short* __restrict__ B1l,
    float* __restrict__ cv) {
    __shared__ float w1[128][128];
    int tid = threadIdx.x;
    #pragma unroll
    for (int it = 0; it < 16; ++it) {
        int s = tid + it * 256;
        int r = s >> 5, c4 = (s & 31) << 2;
        *(float4*)&w1[r][c4] = *(const float4*)&W1[r * 128 + c4];
    }
    __syncthreads();
    int j = tid & 127;
    int half = tid >> 7;
    if (blockIdx.x == 128) {
        if (half) return;
        float sum = 0.f;
        for (int k = 0; k < 128; ++k) sum += be[k] * w1[k][j];
        cv[j] = sum;
        return;
    }
    int i = blockIdx.x * 2 + half;
    const float* arow = &We[i * 128];
    float sum = 0.f;
    for (int k = 0; k < 128; ++k) sum += arow[k] * w1[k][j];
    unsigned short h = f2bf(sum);
    unsigned short l = f2bf(sum - bf2f(h));
    size_t o = bswz_idx(i, j);
    B1h[o] = h; B1l[o] = l;
}

__global__ __launch_bounds__(256) void swizzle_split(
    const float* __restrict__ W, unsigned short* __restrict__ Bh,
    unsigned short* __restrict__ Bl, int K) {
    int idx = blockIdx.x * 256 + threadIdx.x;
    if (idx >= K * 128) return;
    int k = idx >> 7, col = idx & 127;
    float v = W[idx];
    unsigned short h = f2bf(v);
    unsigned short l = f2bf(v - bf2f(h));
    size_t o = bswz_idx(k, col);
    Bh[o] = h; Bl[o] = l;
}

// ---------------------------------------------------------------- MFMA GEMM from bf16 planes; T out = bf16
// A: Xh (and Xl if AL) [n][K] bf16 row-major. B pre-swizzled. 3-term if AL else 2-term.
template <int K, bool AL>
__global__ __launch_bounds__(256) void gemm_planes(
    const unsigned short* __restrict__ Xh, const unsigned short* __restrict__ Xl,
    const unsigned short* __restrict__ Bh, const unsigned short* __restrict__ Bl,
    const float* __restrict__ cvec, const int* __restrict__ degs,
    unsigned short* __restrict__ T, int n) {
    const int tid = threadIdx.x;
    const int wave = tid >> 6;
    const int lane = tid & 63;
    const int lr = lane & 15;
    const int lk = lane >> 4;
    const int row0 = blockIdx.x * 128 + wave * 32;

    f32x4 acc[2][8];
    #pragma unroll
    for (int rt = 0; rt < 2; ++rt)
        #pragma unroll
        for (int c = 0; c < 8; ++c) acc[rt][c] = (f32x4)0.f;

    const int r0 = row0 + lr;
    const int r1 = row0 + 16 + lr;
    const bool v0 = r0 < n, v1 = r1 < n;
    const unsigned short* ph0 = Xh + (size_t)r0 * K + lk * 8;
    const unsigned short* ph1 = Xh + (size_t)r1 * K + lk * 8;
    const unsigned short* pl0 = AL ? Xl + (size_t)r0 * K + lk * 8 : nullptr;
    const unsigned short* pl1 = AL ? Xl + (size_t)r1 * K + lk * 8 : nullptr;
    const bf16x8* pBh = (const bf16x8*)Bh;
    const bf16x8* pBl = (const bf16x8*)Bl;

    for (int s = 0; s < K / 32; ++s) {
        bf16x8 ah0 = (bf16x8)0, ah1 = (bf16x8)0, al0 = (bf16x8)0, al1 = (bf16x8)0;
        if (v0) ah0 = *(const bf16x8*)(ph0 + s * 32);
        if (v1) ah1 = *(const bf16x8*)(ph1 + s * 32);
        if (AL) {
            if (v0) al0 = *(const bf16x8*)(pl0 + s * 32);
            if (v1) al1 = *(const bf16x8*)(pl1 + s * 32);
        }
        const int fbase = s * 8 * 64 + lane;
        #pragma unroll
        for (int c = 0; c < 8; ++c) {
            bf16x8 bh = pBh[fbase + c * 64];
            bf16x8 bl = pBl[fbase + c * 64];
            acc[0][c] = __builtin_amdgcn_mfma_f32_16x16x32_bf16(ah0, bh, acc[0][c], 0, 0, 0);
            acc[0][c] = __builtin_amdgcn_mfma_f32_16x16x32_bf16(ah0, bl, acc[0][c], 0, 0, 0);
            acc[1][c] = __builtin_amdgcn_mfma_f32_16x16x32_bf16(ah1, bh, acc[1][c], 0, 0, 0);
            acc[1][c] = __builtin_amdgcn_mfma_f32_16x16x32_bf16(ah1, bl, acc[1][c], 0, 0, 0);
            if (AL) {
                acc[0][c] = __builtin_amdgcn_mfma_f32_16x16x32_bf16(al0, bh, acc[0][c], 0, 0, 0);
                acc[1][c] = __builtin_amdgcn_mfma_f32_16x16x32_bf16(al1, bh, acc[1][c], 0, 0, 0);
            }
        }
    }

    #pragma unroll
    for (int rt = 0; rt < 2; ++rt) {
        #pragma unroll
        for (int r = 0; r < 4; ++r) {
            int grow = row0 + rt * 16 + lk * 4 + r;
            if (grow >= n) continue;
            float norm = rsqrtf(fmaxf((float)degs[grow], 1.0f));
            #pragma unroll
            for (int c = 0; c < 8; ++c) {
                float v = acc[rt][c][r];
                if (cvec) v += cvec[c * 16 + lr];
                T[(size_t)grow * 128 + c * 16 + lr] = f2bf(v * norm);
            }
        }
    }
}

// ---------------------------------------------------------------- aggregate: out = relu(norm_dst * sum T[csr[e]] + bias)
// T bf16 [n][128]; wave gathers 2 rows/inst (32 lanes x 8B). OUT_BF16: h1 path, else fp32 d_out.
template <bool OUT_BF16>
__global__ __launch_bounds__(256) void aggregate(
    const unsigned short* __restrict__ T, const int* __restrict__ rowptr,
    const int* __restrict__ csr, const float* __restrict__ bias,
    void* __restrict__ out_, int n) {
    const int wave = threadIdx.x >> 6;
    const int lane = threadIdx.x & 63;
    const int half = lane >> 5;
    const int l32 = lane & 31;
    const int node = blockIdx.x * 4 + wave;
    if (node >= n) return;
    const int beg = rowptr[node], end = rowptr[node + 1];
    float a0 = 0.f, a1 = 0.f, a2 = 0.f, a3 = 0.f;
    int e = beg;
    for (; e + 7 < end; e += 8) {
        #pragma unroll
        for (int j = 0; j < 4; ++j) {
            int sidx = csr[e + j * 2 + half];
            uint2 u = *(const uint2*)&T[(size_t)sidx * 128 + l32 * 4];
            a0 += __uint_as_float(u.x << 16);
            a1 += __uint_as_float(u.x & 0xffff0000u);
            a2 += __uint_as_float(u.y << 16);
            a3 += __uint_as_float(u.y & 0xffff0000u);
        }
    }
    for (; e < end; ++e) {
        if (half == 0) {
            int sidx = csr[e];
            uint2 u = *(const uint2*)&T[(size_t)sidx * 128 + l32 * 4];
            a0 += __uint_as_float(u.x << 16);
            a1 += __uint_as_float(u.x & 0xffff0000u);
            a2 += __uint_as_float(u.y << 16);
            a3 += __uint_as_float(u.y & 0xffff0000u);
        }
    }
    a0 += __shfl_xor(a0, 32);
    a1 += __shfl_xor(a1, 32);
    a2 += __shfl_xor(a2, 32);
    a3 += __shfl_xor(a3, 32);
    if (half == 0) {
        float norm = rsqrtf(fmaxf((float)(end - beg), 1.0f));
        float4 bv = *(const float4*)&bias[l32 * 4];
        float o0 = fmaxf(a0 * norm + bv.x, 0.f);
        float o1 = fmaxf(a1 * norm + bv.y, 0.f);
        float o2 = fmaxf(a2 * norm + bv.z, 0.f);
        float o3 = fmaxf(a3 * norm + bv.w, 0.f);
        if (OUT_BF16) {
            unsigned w0 = (unsigned)f2bf(o0) | ((unsigned)f2bf(o1) << 16);
            unsigned w1 = (unsigned)f2bf(o2) | ((unsigned)f2bf(o3) << 16);
            uint2* dst = (uint2*)((unsigned short*)out_ + (size_t)node * 128 + l32 * 4);
            *dst = make_uint2(w0, w1);
        } else {
            float4* dst = (float4*)((float*)out_ + (size_t)node * 128 + l32 * 4);
            *dst = make_float4(o0, o1, o2, o3);
        }
    }
}

// ---------------------------------------------------------------- launch
extern "C" void kernel_launch(void* const* d_in, const int* in_sizes, int n_in,
                              void* d_out, int out_size, void* d_ws, size_t ws_size,
                              hipStream_t stream) {
    const float* x   = (const float*)d_in[0];
    const float* We  = (const float*)d_in[1];
    const float* be  = (const float*)d_in[2];
    const float* W1  = (const float*)d_in[3];
    const float* b1  = (const float*)d_in[4];
    const float* W2  = (const float*)d_in[5];
    const float* b2  = (const float*)d_in[6];
    const int* src0  = (const int*)d_in[7];
    const int* dst0  = (const int*)d_in[8];
    const int* src1  = (const int*)d_in[9];
    const int* dst1  = (const int*)d_in[10];
    float* out = (float*)d_out;

    const int n = in_sizes[0] / 256;   // 100000
    const int E = in_sizes[7];         // 1600000
    const int chunk = (E + NB - 1) / NB;

    char* p = (char*)d_ws;
    auto carve = [&](size_t bytes) -> void* {
        void* r = (void*)p;
        p += (bytes + 511) & ~(size_t)511;
        return r;
    };
    unsigned short* t        = (unsigned short*)carve((size_t)n * HID * 2);
    unsigned*       bucketed = (unsigned*)carve((size_t)4 * E * 4);
    int*            counts   = (int*)carve((size_t)M4 * 4);
    int*            partials = (int*)carve(1024 * 4);
    int*            rowptr0  = (int*)carve(((size_t)n + 1) * 4);
    int*            rowptr1  = (int*)carve(((size_t)n + 1) * 4);
    int*            dout0    = (int*)carve((size_t)n * 4);
    int*            dout1    = (int*)carve((size_t)n * 4);
    unsigned short* B1h      = (unsigned short*)carve(256 * HID * 2);
    unsigned short* B1l      = (unsigned short*)carve(256 * HID * 2);
    unsigned short* B2h      = (unsigned short*)carve(128 * HID * 2);
    unsigned short* B2l      = (unsigned short*)carve(128 * HID * 2);
    float*          cv       = (float*)carve(HID * 4);
    unsigned short* Xh       = (unsigned short*)carve((size_t)n * 256 * 2);  // 51.2 MB
    unsigned short* Xl       = (unsigned short*)d_out;   // exactly n*128*4 bytes = n*256*2 — consumed by gemm1
    unsigned short* h1       = Xh;                       // overlays Xh (Xh dead after gemm1)

    int* csr0 = (int*)bucketed;
    int* csr1 = (int*)bucketed + E;

    const int gGemm = (n + 127) / 128;
    const int gAgg  = (n + 3) / 4;
    const int gScanA = (M4 + 1023) / 1024;
    const int gScanC = (M4 + 255) / 256;

    // --- X split (Xl lives in d_out; overwritten by final aggregate) ---
    split_x<<<2048, 256, 0, stream>>>(x, Xh, Xl, (long)n * 64);

    // --- graph build (zero global atomics) ---
    bucket_count_all<<<NB, 256, 0, stream>>>(dst0, dst1, src0, src1, counts, E, chunk);
    scan_a<<<gScanA, 256, 0, stream>>>(counts, partials, M4);
    scan_b<<<1, 1024, 0, stream>>>(partials, gScanA);
    scan_c<<<gScanC, 256, 0, stream>>>(counts, partials, M4);
    bucket_scatter_all<<<NB, 256, 0, stream>>>(dst0, dst1, src0, src1, src0, src1,
                                               counts, bucketed, E, chunk);
    bucket_finalize<<<4 * NBUCK, 256, 0, stream>>>(bucketed, counts, rowptr0, rowptr1, dout0, dout1, n, E);

    // --- weights ---
    weight_fuse<<<129, 256, 0, stream>>>(We, be, W1, B1h, B1l, cv);
    swizzle_split<<<(128 * 128 + 255) / 256, 256, 0, stream>>>(W2, B2h, B2l, 128);

    // --- network ---
    gemm_planes<256, true><<<gGemm, 256, 0, stream>>>(Xh, Xl, B1h, B1l, cv, dout0, t, n);
    aggregate<true><<<gAgg, 256, 0, stream>>>(t, rowptr0, csr0, b1, (void*)h1, n);
    gemm_planes<128, false><<<gGemm, 256, 0, stream>>>(h1, nullptr, B2h, B2l, nullptr, dout1, t, n);
    aggregate<false><<<gAgg, 256, 0, stream>>>(t, rowptr1, csr1, b2, (void*)out, n);
}